// Round 19
// baseline (194.465 us; speedup 1.0000x reference)
//
#include <hip/hip_runtime.h>
#include <hip/hip_bf16.h>
#include <stdint.h>

#define E_DIM 1024
#define H_NUM 16
#define D_DIM 64
#define B_NUM 4
#define S_LEN 2048
#define M_DIM (B_NUM * S_LEN)  // 8192
#define KVB 64
#define NT (S_LEN / KVB)       // 32

typedef short bf16x8 __attribute__((ext_vector_type(8)));
typedef float f32x4 __attribute__((ext_vector_type(4)));
typedef float f32x16 __attribute__((ext_vector_type(16)));
typedef unsigned short u16;
typedef unsigned int u32;
typedef u16 u16x4 __attribute__((ext_vector_type(4)));
typedef u16 u16x8 __attribute__((ext_vector_type(8)));
typedef u32 u32x2 __attribute__((ext_vector_type(2)));
typedef float fl4 __attribute__((ext_vector_type(4)));

typedef const __attribute__((address_space(1))) void* gas_ptr;
typedef __attribute__((address_space(3))) void* las_ptr;

__device__ __forceinline__ u16 f2bf(float f) {
    uint32_t u = __builtin_bit_cast(uint32_t, f);
    u += 0x7fffu + ((u >> 16) & 1u);   // RNE (inputs finite)
    return (u16)(u >> 16);
}

// v_cvt_pk_bf16_f32 (proven in passing r8/r10/r11/r12/r16/r17)
__device__ __forceinline__ u32 cvtpk(float lo, float hi) {
    u32 r;
    asm("v_cvt_pk_bf16_f32 %0, %1, %2" : "=v"(r) : "v"(lo), "v"(hi));
    return r;
}

__device__ __forceinline__ void gload16(const u16* g, u16* l) {
    __builtin_amdgcn_global_load_lds((gas_ptr)g, (las_ptr)l, 16, 0, 0);
}

// ---------------- fused fp32 -> bf16 conversion (all 5 tensors) ----------
__global__ __launch_bounds__(256) void cvt_all(const float* __restrict__ hsrc,
                                               const float* __restrict__ w0, const float* __restrict__ w1,
                                               const float* __restrict__ w2, const float* __restrict__ w3,
                                               u16* __restrict__ oh,
                                               u16* o0, u16* o1, u16* o2, u16* o3) {
    const int total = 2097152 + 4 * 262144;  // 3,145,728 vec4 groups
    int idx = blockIdx.x * 256 + threadIdx.x;
    int stride = gridDim.x * 256;
    for (int i = idx; i < total; i += stride) {
        const float* src;
        u16* dst;
        int off;
        if (i < 2097152) {
            src = hsrc; dst = oh; off = i;
        } else {
            int j = i - 2097152;
            int wsel = j >> 18;
            off = j & 262143;
            src = wsel == 0 ? w0 : (wsel == 1 ? w1 : (wsel == 2 ? w2 : w3));
            dst = wsel == 0 ? o0 : (wsel == 1 ? o1 : (wsel == 2 ? o2 : o3));
        }
        fl4 v = ((const fl4*)src)[off];
        u16x4 o;
#pragma unroll
        for (int j2 = 0; j2 < 4; j2++) o[j2] = f2bf(v[j2]);
        ((u16x4*)dst)[off] = o;
    }
}

// ---------------- shared GEMM K-loop (r12-proven structure) --------------
__device__ __forceinline__ void gemm_loop(const u16* __restrict__ A, const u16* __restrict__ Bw,
                                          int m0, int n0, u16* Ash, u16* Bsh,
                                          f32x4 (&acc)[4][4]) {
    const int t = threadIdx.x, w = t >> 6, lane = t & 63;
    const int li = lane & 15, lg = lane >> 4;
    const int srow = lane >> 2, scol = (lane & 3) * 8;
    const int wr = (w >> 1) * 64, wc = (w & 1) * 64;
    const int K = 1024;

    for (int k0 = 0; k0 < K; k0 += 32) {
#pragma unroll
        for (int r = 0; r < 2; r++) {
            int rowbase = r * 64 + w * 16;
            gload16(A + (size_t)(m0 + rowbase + srow) * K + k0 + scol, Ash + rowbase * 32);
            gload16(Bw + (size_t)(n0 + rowbase + srow) * K + k0 + scol, Bsh + rowbase * 32);
        }
        __syncthreads();
        bf16x8 af[4], bfr[4];
#pragma unroll
        for (int i = 0; i < 4; i++)
            af[i] = *(const bf16x8*)&Ash[(wr + i * 16 + li) * 32 + lg * 8];
#pragma unroll
        for (int j = 0; j < 4; j++)
            bfr[j] = *(const bf16x8*)&Bsh[(wc + j * 16 + li) * 32 + lg * 8];
#pragma unroll
        for (int i = 0; i < 4; i++)
#pragma unroll
            for (int j = 0; j < 4; j++)
                acc[i][j] = __builtin_amdgcn_mfma_f32_16x16x32_bf16(af[i], bfr[j], acc[i][j], 0, 0, 0);
        __syncthreads();
    }
}

// epilogue helpers ---------------------------------------------------------
__device__ __forceinline__ void epi_qk(f32x4 (&acc)[4][4], const float* bias, u16* o,
                                       int m0, int n0) {
    const int t = threadIdx.x, w = t >> 6, lane = t & 63;
    const int li = lane & 15, lg = lane >> 4;
    const int wr = (w >> 1) * 64, wc = (w & 1) * 64;
#pragma unroll
    for (int i = 0; i < 4; i++)
#pragma unroll
        for (int j = 0; j < 4; j++) {
            const int col = n0 + wc + j * 16 + li;
            const float bv = bias[col];
            const int hh = col >> 6, dd = col & 63;
#pragma unroll
            for (int ri = 0; ri < 4; ri++) {
                int row = m0 + wr + i * 16 + lg * 4 + ri;
                int bb = row >> 11, ss = row & 2047;
                o[((size_t)(bb * H_NUM + hh) * S_LEN + ss) * D_DIM + dd] =
                    f2bf(acc[i][j][ri] + bv);
            }
        }
}

__device__ __forceinline__ void epi_vt(f32x4 (&acc)[4][4], const float* bias, u16* o,
                                       int m0, int n0) {
    const int t = threadIdx.x, w = t >> 6, lane = t & 63;
    const int li = lane & 15, lg = lane >> 4;
    const int wr = (w >> 1) * 64, wc = (w & 1) * 64;
#pragma unroll
    for (int i = 0; i < 4; i++)
#pragma unroll
        for (int j = 0; j < 4; j++) {
            const int col = n0 + wc + j * 16 + li;
            const float bv = bias[col];
            const int hh = col >> 6, dd = col & 63;
            int row0 = m0 + wr + i * 16 + lg * 4;
            int bb = row0 >> 11, ss = row0 & 2047;
            u16x4 pk;
#pragma unroll
            for (int ri = 0; ri < 4; ri++) pk[ri] = f2bf(acc[i][j][ri] + bv);
            *(u16x4*)&o[((size_t)(bb * H_NUM + hh) * D_DIM + dd) * S_LEN + ss] = pk;
        }
}

// fused QKV projection: flat grid 1536, XCD m-stripe swizzle (r12-proven)
__global__ __launch_bounds__(256) void gemm_qkv(const u16* __restrict__ A,
                                                const u16* __restrict__ W0, const u16* __restrict__ W1,
                                                const u16* __restrict__ W2,
                                                const float* __restrict__ b0, const float* __restrict__ b1,
                                                const float* __restrict__ b2,
                                                u16* Qo, u16* Ko, u16* Vo) {
    __shared__ u16 Ash[128 * 32];
    __shared__ u16 Bsh[128 * 32];
    const int bid = blockIdx.x;
    const int xcd = bid & 7, slot = bid >> 3;   // slot 0..191
    const int zn = slot >> 3, mi = slot & 7;    // zn 0..23
    const int m_t = xcd * 8 + mi;               // 0..63
    const int z = zn >> 3, n_t = zn & 7;        // z 0..2, n 0..7
    const u16* Bw = z == 0 ? W0 : (z == 1 ? W1 : W2);
    const float* bias = z == 0 ? b0 : (z == 1 ? b1 : b2);
    const int m0 = m_t * 128, n0 = n_t * 128;
    f32x4 acc[4][4] = {};
    gemm_loop(A, Bw, m0, n0, Ash, Bsh, acc);
    if (z == 0) epi_qk(acc, bias, Qo, m0, n0);
    else if (z == 1) epi_qk(acc, bias, Ko, m0, n0);
    else epi_vt(acc, bias, Vo, m0, n0);
}

// final output projection: flat grid 512, same XCD m-stripe swizzle; fp32 out
__global__ __launch_bounds__(256) void gemm_out(const u16* __restrict__ A, const u16* __restrict__ Bw,
                                                const float* __restrict__ bias, float* __restrict__ o) {
    __shared__ u16 Ash[128 * 32];
    __shared__ u16 Bsh[128 * 32];
    const int bid = blockIdx.x;
    const int xcd = bid & 7, slot = bid >> 3;   // slot 0..63
    const int n_t = slot >> 3, mi = slot & 7;
    const int m_t = xcd * 8 + mi;
    const int m0 = m_t * 128, n0 = n_t * 128;
    f32x4 acc[4][4] = {};
    gemm_loop(A, Bw, m0, n0, Ash, Bsh, acc);
    const int t = threadIdx.x, w = t >> 6, lane = t & 63;
    const int li = lane & 15, lg = lane >> 4;
    const int wr = (w >> 1) * 64, wc = (w & 1) * 64;
#pragma unroll
    for (int i = 0; i < 4; i++)
#pragma unroll
        for (int j = 0; j < 4; j++) {
            const int col = n0 + wc + j * 16 + li;
            const float bv = bias[col];
#pragma unroll
            for (int ri = 0; ri < 4; ri++) {
                int row = m0 + wr + i * 16 + lg * 4 + ri;
                o[(size_t)row * E_DIM + col] = acc[i][j][ri] + bv;
            }
        }
}

// ---------------- flash attention: r17-proven terminal kernel ------------
// 512 threads / 8 warps, q-tile 256 rows/block, grid 512; dbuf K+V staging
// via global_load_lds w16 with pre-swizzled source + XOR'd reads (rule #21);
// counted vmcnt(2) + raw barriers (never vmcnt 0 in loop); fixed-shift
// softmax (cancels in o/l); cvt_pk packing; per-warp XOR-swizzled P LDS
// round-trip; XCD-balanced bijective head remap. FROZEN: r14/r15/r18
// restructures all failed on HW despite clean audits — needs unit probes.
__global__ __launch_bounds__(512) void attn_kernel(const u16* __restrict__ Qg,
                                                   const u16* __restrict__ Kg,
                                                   const u16* __restrict__ Vt,
                                                   u16* __restrict__ attn_out,
                                                   const int* __restrict__ actp) {
    const int bid = blockIdx.x;
    const int xcd = bid & 7, slot = bid >> 3;   // slot 0..63
    const int jg = slot >> 3, qblk = slot & 7;  // jg = head-group 0..7
    const int bh = jg * 8 + ((xcd + jg) & 7);   // balanced, bijective
    const int h = bh & (H_NUM - 1), b = bh >> 4;
    const int t = threadIdx.x, w = t >> 6, lane = t & 63;
    const int ql = lane & 31, hi = lane >> 5;
    const int active = *actp;

    if (h >= active) {  // masked head: zero 256 rows x 64 cols
        int row = qblk * 256 + (t >> 1);
        u16* dst = attn_out + (size_t)(b * S_LEN + row) * E_DIM + h * D_DIM + (t & 1) * 32;
        u16x8 z = {};
        *(u16x8*)(dst + 0) = z;
        *(u16x8*)(dst + 8) = z;
        *(u16x8*)(dst + 16) = z;
        *(u16x8*)(dst + 24) = z;
        return;
    }

    const int q0 = qblk * 256 + w * 32;
    const size_t hoff = (size_t)(b * H_NUM + h) * S_LEN * D_DIM;
    const u16* Qh = Qg + hoff;
    const u16* Kh = Kg + hoff;
    const u16* Vh = Vt + hoff;  // [D][S]

    __shared__ __align__(16) u16 Ksh[2][64 * 64];  // 16KB dbuf
    __shared__ __align__(16) u16 Vsh[2][64 * 64];  // 16KB dbuf
    __shared__ __align__(16) u16 Pl[8][2048];      // per-warp P, 32KB

    char* Pb = (char*)&Pl[w][0] + ql * 128;
    const int sw = (ql & 7) << 4;

    const int srow0 = t >> 3, scolb = (t & 7) << 4;
    const int sc0 = (scolb ^ ((srow0 & 7) << 4)) >> 1;

    auto stage = [&](int buf, int kv0) {
        gload16(Kh + (size_t)(kv0 + srow0) * D_DIM + sc0, &Ksh[buf][t * 8]);
        gload16(Vh + (size_t)srow0 * S_LEN + kv0 + sc0, &Vsh[buf][t * 8]);
    };

    bf16x8 qf[4];
#pragma unroll
    for (int dch = 0; dch < 4; dch++)
        qf[dch] = *(const bf16x8*)&Qh[(size_t)(q0 + ql) * D_DIM + dch * 16 + hi * 8];

    f32x16 o0 = {}, o1 = {};
    float l_run = 0.f;
    const float Cs = 0.125f * 1.44269504f;  // scale * log2(e)
    const float mt = 16.0f * Cs;            // fixed shift (cancels in o/l)

    stage(0, 0);
    for (int it = 0; it < NT; ++it) {
        const int cur = it & 1;
        stage(cur ^ 1, ((it + 1) & (NT - 1)) * KVB);
        asm volatile("s_waitcnt vmcnt(2)" ::: "memory");  // own stage(it) landed
        __builtin_amdgcn_sched_barrier(0);
        __builtin_amdgcn_s_barrier();                      // tile(it) visible block-wide

        char* Kc = (char*)&Ksh[cur][0];
        char* Vc = (char*)&Vsh[cur][0];

        // ---- QK^T from LDS K frags
        f32x16 s0 = {}, s1 = {};
#pragma unroll
        for (int d = 0; d < 4; d++) {
            bf16x8 k0 = *(const bf16x8*)(Kc + ql * 128 + ((d * 32 + hi * 16) ^ sw));
            bf16x8 k1 = *(const bf16x8*)(Kc + (32 + ql) * 128 + ((d * 32 + hi * 16) ^ sw));
            s0 = __builtin_amdgcn_mfma_f32_32x32x16_bf16(k0, qf[d], s0, 0, 0, 0);
            s1 = __builtin_amdgcn_mfma_f32_32x32x16_bf16(k1, qf[d], s1, 0, 0, 0);
        }

        // ---- P = exp2(Cs*s - mt); pack via cvt_pk; paired sum
        float p0[16], p1[16];
#pragma unroll
        for (int j = 0; j < 16; j++) {
            p0[j] = __builtin_amdgcn_exp2f(__builtin_fmaf(s0[j], Cs, -mt));
            p1[j] = __builtin_amdgcn_exp2f(__builtin_fmaf(s1[j], Cs, -mt));
        }
        u32 pk0[8], pk1[8];
        float ls = 0.f;
#pragma unroll
        for (int i = 0; i < 8; i++) {
            pk0[i] = cvtpk(p0[2 * i], p0[2 * i + 1]);
            pk1[i] = cvtpk(p1[2 * i], p1[2 * i + 1]);
            ls += (p0[2 * i] + p0[2 * i + 1]) + (p1[2 * i] + p1[2 * i + 1]);
        }
        ls += __shfl_xor(ls, 32, 64);
        l_run += ls;

        // ---- WAR: previous tile's P reads drain before overwrite
        asm volatile("s_waitcnt lgkmcnt(0)" ::: "memory");
        __builtin_amdgcn_sched_barrier(0);

        // ---- store P^T as u32x2: slot s covers kv 8s..8s+7 of own q-row
#pragma unroll
        for (int s = 0; s < 4; s++) {
            u32x2 va = {pk0[2 * s], pk0[2 * s + 1]};
            u32x2 vb = {pk1[2 * s], pk1[2 * s + 1]};
            *(u32x2*)(Pb + ((s * 16 + hi * 8) ^ sw)) = va;
            *(u32x2*)(Pb + ((64 + s * 16 + hi * 8) ^ sw)) = vb;
        }

        // ---- RAW: stores visible before cross-lane P reads
        asm volatile("s_waitcnt lgkmcnt(0)" ::: "memory");
        __builtin_amdgcn_sched_barrier(0);

        // ---- PV: O^T += V^T x P^T from LDS V frags
#pragma unroll
        for (int c = 0; c < 4; c++) {
            bf16x8 pb = *(const bf16x8*)(Pb + ((c * 32 + hi * 16) ^ sw));
            bf16x8 v0 = *(const bf16x8*)(Vc + ql * 128 + ((c * 32 + hi * 16) ^ sw));
            bf16x8 v1 = *(const bf16x8*)(Vc + (32 + ql) * 128 + ((c * 32 + hi * 16) ^ sw));
            o0 = __builtin_amdgcn_mfma_f32_32x32x16_bf16(v0, pb, o0, 0, 0, 0);
            o1 = __builtin_amdgcn_mfma_f32_32x32x16_bf16(v1, pb, o1, 0, 0, 0);
        }

        __builtin_amdgcn_s_barrier();  // all reads of buf[cur] done before overwrite
    }

    // ---- epilogue: normalize, bf16, store [B*S, E]
    const float inv = 1.0f / l_run;
    u16* dst = attn_out + (size_t)(b * S_LEN + q0 + ql) * E_DIM + h * D_DIM;
#pragma unroll
    for (int g = 0; g < 4; g++) {
        u16x4 w0, w1;
#pragma unroll
        for (int e = 0; e < 4; e++) {
            w0[e] = f2bf(o0[4 * g + e] * inv);
            w1[e] = f2bf(o1[4 * g + e] * inv);
        }
        *(u16x4*)(dst + 8 * g + 4 * hi) = w0;
        *(u16x4*)(dst + 32 + 8 * g + 4 * hi) = w1;
    }
}

// ---------------- launcher ------------------------------------------------
extern "C" void kernel_launch(void* const* d_in, const int* in_sizes, int n_in,
                              void* d_out, int out_size, void* d_ws, size_t ws_size,
                              hipStream_t stream) {
    const float* hidden = (const float*)d_in[0];
    const float* Wq = (const float*)d_in[1];
    const float* bq = (const float*)d_in[2];
    const float* Wk = (const float*)d_in[3];
    const float* bk = (const float*)d_in[4];
    const float* Wv = (const float*)d_in[5];
    const float* bv = (const float*)d_in[6];
    const float* Wo = (const float*)d_in[7];
    const float* bo = (const float*)d_in[8];
    const int* act = (const int*)d_in[9];

    u16* ws = (u16*)d_ws;
    u16* Xb = ws;                    // [8192,1024] bf16
    u16* Wqb = Xb + 8388608;
    u16* Wkb = Wqb + 1048576;
    u16* Wvb = Wkb + 1048576;
    u16* Wob = Wvb + 1048576;
    u16* Qb = Wob + 1048576;         // [B,H,S,D]
    u16* Kb = Qb + 8388608;          // [B,H,S,D]
    u16* Vtb = Kb + 8388608;         // [B,H,D,S]
    u16* Att = Vtb + 8388608;        // [8192,1024]

    cvt_all<<<2048, 256, 0, stream>>>(hidden, Wq, Wk, Wv, Wo, Xb, Wqb, Wkb, Wvb, Wob);

    gemm_qkv<<<1536, 256, 0, stream>>>(Xb, Wqb, Wkb, Wvb, bq, bk, bv, Qb, Kb, Vtb);

    attn_kernel<<<512, 512, 0, stream>>>(Qb, Kb, Vtb, Att, act);

    gemm_out<<<512, 256, 0, stream>>>(Att, Wob, bo, (float*)d_out);
}